// Round 19
// baseline (209.164 us; speedup 1.0000x reference)
//
#include <hip/hip_runtime.h>
#include <hip/hip_bf16.h>

typedef unsigned short u16;
typedef unsigned int u32;
typedef __bf16 bf16x8 __attribute__((ext_vector_type(8)));
typedef float f32x4 __attribute__((ext_vector_type(4)));

#define AS1 __attribute__((address_space(1)))
#define AS3 __attribute__((address_space(3)))

__device__ __forceinline__ u16 f2bf(float f) {
  unsigned u = __builtin_bit_cast(unsigned, f);
  u += 0x7FFFu + ((u >> 16) & 1u);
  return (u16)(u >> 16);
}

__device__ __forceinline__ void gload_lds16(const void* g, void* l) {
  __builtin_amdgcn_global_load_lds((AS1 void*)g, (AS3 void*)l, 16, 0, 0);
}

// ---------------- unified conversion: x + weights + bias, ONE launch --------
__global__ __launch_bounds__(256)
void cvt_all(const float* __restrict__ x,
             const float* __restrict__ Wq, const float* __restrict__ Wk,
             const float* __restrict__ Wv, const float* __restrict__ Wo,
             const float* __restrict__ bq, const float* __restrict__ bk,
             const float* __restrict__ bv,
             u16* __restrict__ xb, u16* __restrict__ wqkv, u16* __restrict__ wo,
             float* __restrict__ bias_a, float qs) {
  const long NX = 1048576, NQ = 524288, NK = 32768, NV = 32768, NO = 524288;
  const long NW = NX + NQ + NK + NV + NO;
  long i = (long)blockIdx.x * 256 + threadIdx.x;
  if (i >= NW) {  // bias tail
    int t = (int)(i - NW);
    if (t < 2048) bias_a[t] = bq[t] * qs;
    else if (t < 2176) bias_a[t] = bk[t - 2048];
    else if (t < 2304) bias_a[t] = bv[t - 2176];
    return;
  }
  const float* src;
  u16* dst;
  float s = 1.f;
  if (i < NX) { src = x + i * 8; dst = xb + i * 8; }
  else if (i < NX + NQ) { long j = i - NX; src = Wq + j * 8; dst = wqkv + j * 8; s = qs; }
  else if (i < NX + NQ + NK) { long j = i - NX - NQ; src = Wk + j * 8; dst = wqkv + 2048l * 2048 + j * 8; }
  else if (i < NX + NQ + NK + NV) { long j = i - NX - NQ - NK; src = Wv + j * 8; dst = wqkv + 2176l * 2048 + j * 8; }
  else { long j = i - NX - NQ - NK - NV; src = Wo + j * 8; dst = wo + j * 8; }
  float4 a = *(const float4*)src;
  float4 b = *(const float4*)(src + 4);
  u16 t[8] = {f2bf(a.x * s), f2bf(a.y * s), f2bf(a.z * s), f2bf(a.w * s),
              f2bf(b.x * s), f2bf(b.y * s), f2bf(b.z * s), f2bf(b.w * s)};
  *(uint4*)dst = *(const uint4*)t;
}

// ---------------- V transpose/permute: V[b*S+t][128] -> VT[b*128+d][2048] ----
// t_lin within each 64-t tile: t_lin = ((t>>5)&1)*32 + ((t>>2)&3)*8
//                                    + ((t>>4)&1)*4 + (t&3)
// 2 MB total, L2-resident (V just written by gemm_qkv). 512 blocks.
__global__ __launch_bounds__(256)
void vtrans(const u16* __restrict__ V, u16* __restrict__ VT) {
  int i = blockIdx.x * 256 + threadIdx.x;   // 131072 threads, 4 t-rows each
  int b = i >> 16;
  int rem = i & 65535;
  int d = rem & 127;           // consecutive lanes -> consecutive d (coalesced reads)
  int t0 = (rem >> 7) << 2;
  u16 v0 = V[((long)b * 2048 + t0 + 0) * 128 + d];
  u16 v1 = V[((long)b * 2048 + t0 + 1) * 128 + d];
  u16 v2 = V[((long)b * 2048 + t0 + 2) * 128 + d];
  u16 v3 = V[((long)b * 2048 + t0 + 3) * 128 + d];
  int tl = t0 & 63;
  int base = ((tl >> 5) & 1) * 32 + ((tl >> 2) & 3) * 8 + ((tl >> 4) & 1) * 4;
  u32 lo = (u32)v0 | ((u32)v1 << 16);
  u32 hi = (u32)v2 | ((u32)v3 << 16);
  u32* wp = (u32*)(VT + ((long)b * 128 + d) * 2048 + (t0 >> 6) * 64 + base);
  wp[0] = lo;
  wp[1] = hi;
}

// ---------------- GEMM #1: fused QKV projection ----------------
// C = A @ B^T + bias. BK=64, XOR-swizzled LDS. Grid (18, 32).
// Epilogue: BLOCK-UNIFORM routing, plain row stores only (no in-GEMM
// transpose): tiles 0-15 -> Q rows; tile 16 -> K rows; tile 17 -> V rows
// (vtrans produces the t_lin-permuted V^T afterwards).
__global__ __launch_bounds__(256)
void gemm_qkv(const u16* __restrict__ A, const u16* __restrict__ B,
              const float* __restrict__ bias, u16* __restrict__ Cq,
              u16* __restrict__ Ck, u16* __restrict__ Cv, int K)
{
  __shared__ u16 As[128 * 64];
  __shared__ u16 Bs[128 * 64];
  const int tid = threadIdx.x;
  const int wave = tid >> 6, lane = tid & 63;
  const int g = lane >> 4, r = lane & 15;
  const int wrow = (wave >> 1) * 64, wcol = (wave & 1) * 64;

  const int gx = gridDim.x;
  int lin = blockIdx.y * gx + blockIdx.x;
  const int cpx = (gx * gridDim.y) >> 3;
  lin = (lin & 7) * cpx + (lin >> 3);
  const long tM = (long)(lin / gx) * 128, tN = (long)(lin % gx) * 128;

  const int srow = (tid * 16) >> 7;
  const int scol = (tid & 7) * 8;

  f32x4 acc[4][4] = {};
  char* As3 = (char*)As;
  char* Bs3 = (char*)Bs;

  for (int kt = 0; kt < K; kt += 64) {
    __syncthreads();
#pragma unroll
    for (int p = 0; p < 4; p++) {
      const int row = p * 32 + srow;
      const int sc = scol ^ ((row & 7) << 3);
      gload_lds16(A + (tM + row) * K + kt + sc, As3 + p * 4096 + tid * 16);
      gload_lds16(B + (tN + row) * K + kt + sc, Bs3 + p * 4096 + tid * 16);
    }
    __syncthreads();

#pragma unroll
    for (int kk = 0; kk < 2; kk++) {
      bf16x8 a[4], b[4];
#pragma unroll
      for (int m = 0; m < 4; m++) {
        const int ra = wrow + m * 16 + r;
        a[m] = *(const bf16x8*)(As + ra * 64 + ((kk * 32 + g * 8) ^ ((ra & 7) << 3)));
      }
#pragma unroll
      for (int n = 0; n < 4; n++) {
        const int rb = wcol + n * 16 + r;
        b[n] = *(const bf16x8*)(Bs + rb * 64 + ((kk * 32 + g * 8) ^ ((rb & 7) << 3)));
      }
#pragma unroll
      for (int m = 0; m < 4; m++)
#pragma unroll
        for (int n = 0; n < 4; n++)
          acc[m][n] = __builtin_amdgcn_mfma_f32_16x16x32_bf16(a[m], b[n], acc[m][n], 0, 0, 0);
    }
  }

  if (tN < 2048) {          // Q tiles
#pragma unroll
    for (int m = 0; m < 4; m++) {
      const long row0 = tM + wrow + m * 16 + g * 4;
#pragma unroll
      for (int n = 0; n < 4; n++) {
        const long col = tN + wcol + n * 16 + r;
        const float bb = bias[col];
#pragma unroll
        for (int q = 0; q < 4; q++)
          Cq[(row0 + q) * 2048 + col] = f2bf(acc[m][n][q] + bb);
      }
    }
  } else if (tN < 2176) {   // K tile (cols 2048..2175)
#pragma unroll
    for (int m = 0; m < 4; m++) {
      const long row0 = tM + wrow + m * 16 + g * 4;
#pragma unroll
      for (int n = 0; n < 4; n++) {
        const int col = (int)(tN - 2048) + wcol + n * 16 + r;
        const float bb = bias[col + 2048];
#pragma unroll
        for (int q = 0; q < 4; q++)
          Ck[(row0 + q) * 128 + col] = f2bf(acc[m][n][q] + bb);
      }
    }
  } else {                  // V tile (cols 2176..2303) -> plain rows
#pragma unroll
    for (int m = 0; m < 4; m++) {
      const long row0 = tM + wrow + m * 16 + g * 4;
#pragma unroll
      for (int n = 0; n < 4; n++) {
        const int col = (int)(tN - 2176) + wcol + n * 16 + r;
        const float bb = bias[col + 2176];
#pragma unroll
        for (int q = 0; q < 4; q++)
          Cv[(row0 + q) * 128 + col] = f2bf(acc[m][n][q] + bb);
      }
    }
  }
}

// ---------------- GEMM #2: output projection (unchanged from R18) -----------
__global__ __launch_bounds__(256)
void gemm_out(const u16* __restrict__ A, const u16* __restrict__ B,
              const float* __restrict__ bias, float* __restrict__ C,
              int N, int K)
{
  __shared__ u16 As[128 * 64];
  __shared__ u16 Bs[128 * 64];
  const int tid = threadIdx.x;
  const int wave = tid >> 6, lane = tid & 63;
  const int g = lane >> 4, r = lane & 15;
  const int wrow = (wave >> 1) * 64, wcol = (wave & 1) * 64;

  const int gx = gridDim.x;
  int lin = blockIdx.y * gx + blockIdx.x;
  const int cpx = (gx * gridDim.y) >> 3;
  lin = (lin & 7) * cpx + (lin >> 3);
  const long tM = (long)(lin / gx) * 128, tN = (long)(lin % gx) * 128;

  const int srow = (tid * 16) >> 7;
  const int scol = (tid & 7) * 8;

  f32x4 acc[4][4] = {};
  char* As3 = (char*)As;
  char* Bs3 = (char*)Bs;

  for (int kt = 0; kt < K; kt += 64) {
    __syncthreads();
#pragma unroll
    for (int p = 0; p < 4; p++) {
      const int row = p * 32 + srow;
      const int sc = scol ^ ((row & 7) << 3);
      gload_lds16(A + (tM + row) * K + kt + sc, As3 + p * 4096 + tid * 16);
      gload_lds16(B + (tN + row) * K + kt + sc, Bs3 + p * 4096 + tid * 16);
    }
    __syncthreads();

#pragma unroll
    for (int kk = 0; kk < 2; kk++) {
      bf16x8 a[4], b[4];
#pragma unroll
      for (int m = 0; m < 4; m++) {
        const int ra = wrow + m * 16 + r;
        a[m] = *(const bf16x8*)(As + ra * 64 + ((kk * 32 + g * 8) ^ ((ra & 7) << 3)));
      }
#pragma unroll
      for (int n = 0; n < 4; n++) {
        const int rb = wcol + n * 16 + r;
        b[n] = *(const bf16x8*)(Bs + rb * 64 + ((kk * 32 + g * 8) ^ ((rb & 7) << 3)));
      }
#pragma unroll
      for (int m = 0; m < 4; m++)
#pragma unroll
        for (int n = 0; n < 4; n++)
          acc[m][n] = __builtin_amdgcn_mfma_f32_16x16x32_bf16(a[m], b[n], acc[m][n], 0, 0, 0);
    }
  }

#pragma unroll
  for (int m = 0; m < 4; m++) {
    const long row0 = tM + wrow + m * 16 + g * 4;
#pragma unroll
    for (int n = 0; n < 4; n++) {
      const long col = tN + wcol + n * 16 + r;
      const float bb = bias[col];
#pragma unroll
      for (int q = 0; q < 4; q++)
        C[(row0 + q) * N + col] = acc[m][n][q] + bb;
    }
  }
}

// ---------------- Flash attention, MQA (R17, unchanged) ---------------------
__global__ __launch_bounds__(512, 2)
void attn_mqa15(const u16* __restrict__ Q, const u16* __restrict__ Kb,
                const u16* __restrict__ VT, u16* __restrict__ O)
{
  constexpr int S = 2048;
  const int bid = blockIdx.x;
  const int qt = bid & 7;            // 8 q-tiles of 256 rows
  const int head = (bid >> 3) & 15;
  const int b = bid >> 7;
  const int tid = threadIdx.x;
  const int wave = tid >> 6, lane = tid & 63;  // wave 0..7
  const int g = lane >> 4, r = lane & 15;

  __shared__ u16 Ks[2][64 * 128];   // 32 KB
  __shared__ u16 VTs[2][128 * 64];  // 32 KB -> 64 KB total

  bf16x8 qf[2][4];
#pragma unroll
  for (int qb = 0; qb < 2; qb++) {
    const u16* qp = Q + (long)(b * S + qt * 256 + qb * 128 + wave * 16 + r) * 2048
                      + head * 128 + g * 8;
#pragma unroll
    for (int ks = 0; ks < 4; ks++) qf[qb][ks] = *(const bf16x8*)(qp + ks * 32);
  }

  f32x4 oacc[2][8] = {};
  float lacc[2][4] = {};   // independent partial denominators [qb][reg]

  auto stageK = [&](int buf, int t0) {
    char* dst = (char*)Ks[buf];
#pragma unroll
    for (int p = 0; p < 2; p++) {
      int D = p * 8192 + wave * 1024 + lane * 16;
      int row = D >> 8;
      int col2 = (D & 255) ^ ((row & 7) << 4);
      gload_lds16(Kb + ((long)b * S + t0 + row) * 128 + (col2 >> 1), dst + D);
    }
  };
  auto stageV = [&](int buf, int t0) {
    char* dst = (char*)VTs[buf];
#pragma unroll
    for (int p = 0; p < 2; p++) {
      int D = p * 8192 + wave * 1024 + lane * 16;
      int row = D >> 7;
      int colb = (D & 127) ^ ((row & 7) << 4);
      gload_lds16(VT + ((long)b * 128 + row) * 2048 + t0 + (colb >> 1), dst + D);
    }
  };

  stageK(0, 0);
  stageV(0, 0);
  __syncthreads();

  for (int t0 = 0; t0 < S; t0 += 64) {
    const int cur = (t0 >> 6) & 1;
    const bool nxt = (t0 + 64) < S;

    if (nxt) { stageK(cur ^ 1, t0 + 64); stageV(cur ^ 1, t0 + 64); }

    // QK^T swapped: A = K (t rows), B = Q (q cols).
    char* Ks3 = (char*)Ks[cur];
    f32x4 st[2][4] = {};
    __builtin_amdgcn_s_setprio(1);
#pragma unroll
    for (int ks = 0; ks < 4; ks++) {
#pragma unroll
      for (int nf = 0; nf < 4; nf++) {
        const int trow = nf * 16 + r;
        const int col2 = (ks * 64 + g * 16) ^ ((trow & 7) << 4);
        bf16x8 kf = *(const bf16x8*)(Ks3 + trow * 256 + col2);
        st[0][nf] = __builtin_amdgcn_mfma_f32_16x16x32_bf16(kf, qf[0][ks], st[0][nf], 0, 0, 0);
        st[1][nf] = __builtin_amdgcn_mfma_f32_16x16x32_bf16(kf, qf[1][ks], st[1][nf], 0, 0, 0);
      }
    }
    __builtin_amdgcn_s_setprio(0);

    // in-register softmax + P pack (compiler casts -> packed cvt)
    char* Vs3 = (char*)VTs[cur];
    bf16x8 vreg[2][8];
#pragma unroll
    for (int qb = 0; qb < 2; qb++) {
      bf16x8 pf[2];
#pragma unroll
      for (int ks = 0; ks < 2; ks++) {
        bf16x8 pv;
#pragma unroll
        for (int reg = 0; reg < 4; reg++) {
          float a = __builtin_amdgcn_exp2f(st[qb][ks * 2][reg]);
          float c = __builtin_amdgcn_exp2f(st[qb][ks * 2 + 1][reg]);
          lacc[qb][reg] += a + c;
          pv[reg] = (__bf16)a;
          pv[4 + reg] = (__bf16)c;
        }
        pf[ks] = pv;
      }
      // PV swapped: A = V^T (d rows), B = P (q cols); V frags cached qb0->qb1
      __builtin_amdgcn_s_setprio(1);
#pragma unroll
      for (int ks = 0; ks < 2; ks++) {
#pragma unroll
        for (int dn = 0; dn < 8; dn++) {
          if (qb == 0) {
            const int d = dn * 16 + r;
            vreg[ks][dn] = *(const bf16x8*)(Vs3 + d * 128 +
                                            ((ks * 64 + g * 16) ^ ((d & 7) << 4)));
          }
          oacc[qb][dn] = __builtin_amdgcn_mfma_f32_16x16x32_bf16(vreg[ks][dn], pf[ks],
                                                                 oacc[qb][dn], 0, 0, 0);
        }
      }
      __builtin_amdgcn_s_setprio(0);
    }

    __syncthreads();
  }

  // final denominator: combine partials, then reduce over g (t spread)
  float lsum[2];
#pragma unroll
  for (int qb = 0; qb < 2; qb++) {
    lsum[qb] = (lacc[qb][0] + lacc[qb][1]) + (lacc[qb][2] + lacc[qb][3]);
    lsum[qb] += __shfl_xor(lsum[qb], 16);
    lsum[qb] += __shfl_xor(lsum[qb], 32);
  }

  // epilogue: oacc[qb][dn]: row q = r, d = dn*16 + g*4 + reg
#pragma unroll
  for (int qb = 0; qb < 2; qb++) {
    const float inv = 1.f / lsum[qb];
    const long orow = (long)(b * S + qt * 256 + qb * 128 + wave * 16 + r);
#pragma unroll
    for (int dn = 0; dn < 8; dn++) {
      u16 pk4[4];
#pragma unroll
      for (int reg = 0; reg < 4; reg++) pk4[reg] = f2bf(oacc[qb][dn][reg] * inv);
      *(ushort4*)(O + orow * 2048 + head * 128 + dn * 16 + g * 4) =
          *(const ushort4*)pk4;
    }
  }
}

// ---------------- launch ----------------
extern "C" void kernel_launch(void* const* d_in, const int* in_sizes, int n_in,
                              void* d_out, int out_size, void* d_ws, size_t ws_size,
                              hipStream_t stream) {
  const float* x  = (const float*)d_in[0];
  const float* Wq = (const float*)d_in[1];
  const float* bq = (const float*)d_in[2];
  const float* Wk = (const float*)d_in[3];
  const float* bk = (const float*)d_in[4];
  const float* Wv = (const float*)d_in[5];
  const float* bv = (const float*)d_in[6];
  const float* Wo = (const float*)d_in[7];
  const float* bo = (const float*)d_in[8];
  float* out = (float*)d_out;

  char* ws = (char*)d_ws;
  u16* x_bf     = (u16*)(ws + (0ul  << 20));  // 16 MiB
  u16* q_bf     = (u16*)(ws + (16ul << 20));  // 16 MiB
  u16* wqkv_bf  = (u16*)(ws + (32ul << 20));  // 9 MiB  [2304][2048]
  u16* wo_bf    = (u16*)(ws + (42ul << 20));  // 8 MiB
  u16* k_bf     = (u16*)(ws + (50ul << 20));  // 1 MiB  K   [b*S][128]
  u16* vt_bf    = (u16*)(ws + (51ul << 20));  // 1 MiB  V^T [b*128][2048] t_lin-permuted
  u16* attn_bf  = (u16*)(ws + (52ul << 20));  // 16 MiB
  float* bias_a = (float*)(ws + (68ul << 20));
  u16* v_bf     = (u16*)(ws + (69ul << 20));  // 1 MiB  V rows [b*S+t][128]

  const float QS = 0.12751744f;  // log2(e)/sqrt(128)

  cvt_all<<<8457, 256, 0, stream>>>(x, Wq, Wk, Wv, Wo, bq, bk, bv,
                                    x_bf, wqkv_bf, wo_bf, bias_a, QS);

  // fused QKV projection: [4096,2304]; plain row stores (Q / K / V)
  gemm_qkv<<<dim3(18, 32), 256, 0, stream>>>(
      x_bf, wqkv_bf, bias_a, q_bf, k_bf, v_bf, 2048);
  // V rows -> V^T in t_lin order (2 MB, L2-resident)
  vtrans<<<512, 256, 0, stream>>>(v_bf, vt_bf);
  // attention -> [4096, 2048] bf16 (8-wave blocks, in-register P)
  attn_mqa15<<<256, 512, 0, stream>>>(q_bf, k_bf, vt_bf, attn_bf);
  // out = attn Wo^T + bo  (fp32)
  gemm_out<<<dim3(16, 32), 256, 0, stream>>>(
      attn_bf, wo_bf, bo, out, 2048, 2048);
}

// Round 20
// 194.177 us; speedup vs baseline: 1.0772x; 1.0772x over previous
//
#include <hip/hip_runtime.h>
#include <hip/hip_bf16.h>

typedef unsigned short u16;
typedef unsigned int u32;
typedef __bf16 bf16x8 __attribute__((ext_vector_type(8)));
typedef float f32x4 __attribute__((ext_vector_type(4)));

#define AS1 __attribute__((address_space(1)))
#define AS3 __attribute__((address_space(3)))

__device__ __forceinline__ u16 f2bf(float f) {
  unsigned u = __builtin_bit_cast(unsigned, f);
  u += 0x7FFFu + ((u >> 16) & 1u);
  return (u16)(u >> 16);
}

__device__ __forceinline__ void gload_lds16(const void* g, void* l) {
  __builtin_amdgcn_global_load_lds((AS1 void*)g, (AS3 void*)l, 16, 0, 0);
}

// ---------------- unified conversion: x + weights + bias, ONE launch --------
__global__ __launch_bounds__(256)
void cvt_all(const float* __restrict__ x,
             const float* __restrict__ Wq, const float* __restrict__ Wk,
             const float* __restrict__ Wv, const float* __restrict__ Wo,
             const float* __restrict__ bq, const float* __restrict__ bk,
             const float* __restrict__ bv,
             u16* __restrict__ xb, u16* __restrict__ wqkv, u16* __restrict__ wo,
             float* __restrict__ bias_a, float qs) {
  const long NX = 1048576, NQ = 524288, NK = 32768, NV = 32768, NO = 524288;
  const long NW = NX + NQ + NK + NV + NO;
  long i = (long)blockIdx.x * 256 + threadIdx.x;
  if (i >= NW) {  // bias tail
    int t = (int)(i - NW);
    if (t < 2048) bias_a[t] = bq[t] * qs;
    else if (t < 2176) bias_a[t] = bk[t - 2048];
    else if (t < 2304) bias_a[t] = bv[t - 2176];
    return;
  }
  const float* src;
  u16* dst;
  float s = 1.f;
  if (i < NX) { src = x + i * 8; dst = xb + i * 8; }
  else if (i < NX + NQ) { long j = i - NX; src = Wq + j * 8; dst = wqkv + j * 8; s = qs; }
  else if (i < NX + NQ + NK) { long j = i - NX - NQ; src = Wk + j * 8; dst = wqkv + 2048l * 2048 + j * 8; }
  else if (i < NX + NQ + NK + NV) { long j = i - NX - NQ - NK; src = Wv + j * 8; dst = wqkv + 2176l * 2048 + j * 8; }
  else { long j = i - NX - NQ - NK - NV; src = Wo + j * 8; dst = wo + j * 8; }
  float4 a = *(const float4*)src;
  float4 b = *(const float4*)(src + 4);
  u16 t[8] = {f2bf(a.x * s), f2bf(a.y * s), f2bf(a.z * s), f2bf(a.w * s),
              f2bf(b.x * s), f2bf(b.y * s), f2bf(b.z * s), f2bf(b.w * s)};
  *(uint4*)dst = *(const uint4*)t;
}

// ---------------- GEMM: Q projection (clone of gemm_out's config) -----------
// Q(bf16) = A @ Wq^T + bq (pre-scaled). N=2048, grid (16,32) — the exact
// launch configuration measured fast for gemm_out; bf16 store is the only
// difference.
__global__ __launch_bounds__(256)
void gemm_q(const u16* __restrict__ A, const u16* __restrict__ B,
            const float* __restrict__ bias, u16* __restrict__ C, int K)
{
  __shared__ u16 As[128 * 64];
  __shared__ u16 Bs[128 * 64];
  const int tid = threadIdx.x;
  const int wave = tid >> 6, lane = tid & 63;
  const int g = lane >> 4, r = lane & 15;
  const int wrow = (wave >> 1) * 64, wcol = (wave & 1) * 64;

  const int gx = gridDim.x;
  int lin = blockIdx.y * gx + blockIdx.x;
  const int cpx = (gx * gridDim.y) >> 3;
  lin = (lin & 7) * cpx + (lin >> 3);
  const long tM = (long)(lin / gx) * 128, tN = (long)(lin % gx) * 128;

  const int srow = (tid * 16) >> 7;
  const int scol = (tid & 7) * 8;

  f32x4 acc[4][4] = {};
  char* As3 = (char*)As;
  char* Bs3 = (char*)Bs;

  for (int kt = 0; kt < K; kt += 64) {
    __syncthreads();
#pragma unroll
    for (int p = 0; p < 4; p++) {
      const int row = p * 32 + srow;
      const int sc = scol ^ ((row & 7) << 3);
      gload_lds16(A + (tM + row) * K + kt + sc, As3 + p * 4096 + tid * 16);
      gload_lds16(B + (tN + row) * K + kt + sc, Bs3 + p * 4096 + tid * 16);
    }
    __syncthreads();

#pragma unroll
    for (int kk = 0; kk < 2; kk++) {
      bf16x8 a[4], b[4];
#pragma unroll
      for (int m = 0; m < 4; m++) {
        const int ra = wrow + m * 16 + r;
        a[m] = *(const bf16x8*)(As + ra * 64 + ((kk * 32 + g * 8) ^ ((ra & 7) << 3)));
      }
#pragma unroll
      for (int n = 0; n < 4; n++) {
        const int rb = wcol + n * 16 + r;
        b[n] = *(const bf16x8*)(Bs + rb * 64 + ((kk * 32 + g * 8) ^ ((rb & 7) << 3)));
      }
#pragma unroll
      for (int m = 0; m < 4; m++)
#pragma unroll
        for (int n = 0; n < 4; n++)
          acc[m][n] = __builtin_amdgcn_mfma_f32_16x16x32_bf16(a[m], b[n], acc[m][n], 0, 0, 0);
    }
  }

#pragma unroll
  for (int m = 0; m < 4; m++) {
    const long row0 = tM + wrow + m * 16 + g * 4;
#pragma unroll
    for (int n = 0; n < 4; n++) {
      const long col = tN + wcol + n * 16 + r;
      const float bb = bias[col];
#pragma unroll
      for (int q = 0; q < 4; q++)
        C[(row0 + q) * 2048 + col] = f2bf(acc[m][n][q] + bb);
    }
  }
}

// ---------------- GEMM: KV projection, split-K ----------------
// Partial[kz] = A[:, kz*512:(kz+1)*512] @ Wkv[:, same]^T  (fp32, no bias).
// Grid (2, 32, 4) = 256 blocks, one round. Deterministic (separate buffers).
__global__ __launch_bounds__(256)
void gemm_kv(const u16* __restrict__ A, const u16* __restrict__ B,
             float* __restrict__ P)   // P: [4][4096][256] fp32 partials
{
  __shared__ u16 As[128 * 64];
  __shared__ u16 Bs[128 * 64];
  const int tid = threadIdx.x;
  const int wave = tid >> 6, lane = tid & 63;
  const int g = lane >> 4, r = lane & 15;
  const int wrow = (wave >> 1) * 64, wcol = (wave & 1) * 64;

  const long tM = (long)blockIdx.y * 128;
  const long tN = (long)blockIdx.x * 128;
  const int kz = blockIdx.z;
  const int K = 2048;

  const int srow = (tid * 16) >> 7;
  const int scol = (tid & 7) * 8;

  f32x4 acc[4][4] = {};
  char* As3 = (char*)As;
  char* Bs3 = (char*)Bs;

  for (int kt = kz * 512; kt < (kz + 1) * 512; kt += 64) {
    __syncthreads();
#pragma unroll
    for (int p = 0; p < 4; p++) {
      const int row = p * 32 + srow;
      const int sc = scol ^ ((row & 7) << 3);
      gload_lds16(A + (tM + row) * K + kt + sc, As3 + p * 4096 + tid * 16);
      gload_lds16(B + (tN + row) * K + kt + sc, Bs3 + p * 4096 + tid * 16);
    }
    __syncthreads();

#pragma unroll
    for (int kk = 0; kk < 2; kk++) {
      bf16x8 a[4], b[4];
#pragma unroll
      for (int m = 0; m < 4; m++) {
        const int ra = wrow + m * 16 + r;
        a[m] = *(const bf16x8*)(As + ra * 64 + ((kk * 32 + g * 8) ^ ((ra & 7) << 3)));
      }
#pragma unroll
      for (int n = 0; n < 4; n++) {
        const int rb = wcol + n * 16 + r;
        b[n] = *(const bf16x8*)(Bs + rb * 64 + ((kk * 32 + g * 8) ^ ((rb & 7) << 3)));
      }
#pragma unroll
      for (int m = 0; m < 4; m++)
#pragma unroll
        for (int n = 0; n < 4; n++)
          acc[m][n] = __builtin_amdgcn_mfma_f32_16x16x32_bf16(a[m], b[n], acc[m][n], 0, 0, 0);
    }
  }

  float* Pz = P + (long)kz * 4096 * 256;
#pragma unroll
  for (int m = 0; m < 4; m++) {
    const long row0 = tM + wrow + m * 16 + g * 4;
#pragma unroll
    for (int n = 0; n < 4; n++) {
      const long col = tN + wcol + n * 16 + r;
#pragma unroll
      for (int q = 0; q < 4; q++)
        Pz[(row0 + q) * 256 + col] = acc[m][n][q];
    }
  }
}

// ---------------- KV finish: sum partials + bias -> K rows + V^T (t_lin) ----
__global__ __launch_bounds__(256)
void kv_finish(const float* __restrict__ P, const float* __restrict__ bias,
               u16* __restrict__ Ck, u16* __restrict__ Cvt)
{
  const long i = (long)blockIdx.x * 256 + threadIdx.x;  // 1,048,576 cells
  const int row = (int)(i >> 8);       // 0..4095 (b*2048 + t)
  const int col = (int)(i & 255);      // 0..255
  const long NN = 4096l * 256;
  float v = P[i] + P[i + NN] + P[i + 2 * NN] + P[i + 3 * NN] + bias[2048 + col];
  u16 bv16 = f2bf(v);
  if (col < 128) {
    Ck[(long)row * 128 + col] = bv16;
  } else {
    const int d = col - 128;
    const int b2 = row >> 11;
    const int t = row & 2047;
    const int tl = t & 63;
    const int tlin = ((tl >> 5) & 1) * 32 + ((tl >> 2) & 3) * 8 +
                     ((tl >> 4) & 1) * 4 + (tl & 3);
    Cvt[((long)b2 * 128 + d) * 2048 + (t >> 6) * 64 + tlin] = bv16;
  }
}

// ---------------- GEMM: output projection (unchanged) -----------------------
__global__ __launch_bounds__(256)
void gemm_out(const u16* __restrict__ A, const u16* __restrict__ B,
              const float* __restrict__ bias, float* __restrict__ C,
              int N, int K)
{
  __shared__ u16 As[128 * 64];
  __shared__ u16 Bs[128 * 64];
  const int tid = threadIdx.x;
  const int wave = tid >> 6, lane = tid & 63;
  const int g = lane >> 4, r = lane & 15;
  const int wrow = (wave >> 1) * 64, wcol = (wave & 1) * 64;

  const int gx = gridDim.x;
  int lin = blockIdx.y * gx + blockIdx.x;
  const int cpx = (gx * gridDim.y) >> 3;
  lin = (lin & 7) * cpx + (lin >> 3);
  const long tM = (long)(lin / gx) * 128, tN = (long)(lin % gx) * 128;

  const int srow = (tid * 16) >> 7;
  const int scol = (tid & 7) * 8;

  f32x4 acc[4][4] = {};
  char* As3 = (char*)As;
  char* Bs3 = (char*)Bs;

  for (int kt = 0; kt < K; kt += 64) {
    __syncthreads();
#pragma unroll
    for (int p = 0; p < 4; p++) {
      const int row = p * 32 + srow;
      const int sc = scol ^ ((row & 7) << 3);
      gload_lds16(A + (tM + row) * K + kt + sc, As3 + p * 4096 + tid * 16);
      gload_lds16(B + (tN + row) * K + kt + sc, Bs3 + p * 4096 + tid * 16);
    }
    __syncthreads();

#pragma unroll
    for (int kk = 0; kk < 2; kk++) {
      bf16x8 a[4], b[4];
#pragma unroll
      for (int m = 0; m < 4; m++) {
        const int ra = wrow + m * 16 + r;
        a[m] = *(const bf16x8*)(As + ra * 64 + ((kk * 32 + g * 8) ^ ((ra & 7) << 3)));
      }
#pragma unroll
      for (int n = 0; n < 4; n++) {
        const int rb = wcol + n * 16 + r;
        b[n] = *(const bf16x8*)(Bs + rb * 64 + ((kk * 32 + g * 8) ^ ((rb & 7) << 3)));
      }
#pragma unroll
      for (int m = 0; m < 4; m++)
#pragma unroll
        for (int n = 0; n < 4; n++)
          acc[m][n] = __builtin_amdgcn_mfma_f32_16x16x32_bf16(a[m], b[n], acc[m][n], 0, 0, 0);
    }
  }

#pragma unroll
  for (int m = 0; m < 4; m++) {
    const long row0 = tM + wrow + m * 16 + g * 4;
#pragma unroll
    for (int n = 0; n < 4; n++) {
      const long col = tN + wcol + n * 16 + r;
      const float bb = bias[col];
#pragma unroll
      for (int q = 0; q < 4; q++)
        C[(row0 + q) * N + col] = acc[m][n][q] + bb;
    }
  }
}

// ---------------- Flash attention, MQA (R17, unchanged) ---------------------
__global__ __launch_bounds__(512, 2)
void attn_mqa15(const u16* __restrict__ Q, const u16* __restrict__ Kb,
                const u16* __restrict__ VT, u16* __restrict__ O)
{
  constexpr int S = 2048;
  const int bid = blockIdx.x;
  const int qt = bid & 7;            // 8 q-tiles of 256 rows
  const int head = (bid >> 3) & 15;
  const int b = bid >> 7;
  const int tid = threadIdx.x;
  const int wave = tid >> 6, lane = tid & 63;  // wave 0..7
  const int g = lane >> 4, r = lane & 15;

  __shared__ u16 Ks[2][64 * 128];   // 32 KB
  __shared__ u16 VTs[2][128 * 64];  // 32 KB -> 64 KB total

  bf16x8 qf[2][4];
#pragma unroll
  for (int qb = 0; qb < 2; qb++) {
    const u16* qp = Q + (long)(b * S + qt * 256 + qb * 128 + wave * 16 + r) * 2048
                      + head * 128 + g * 8;
#pragma unroll
    for (int ks = 0; ks < 4; ks++) qf[qb][ks] = *(const bf16x8*)(qp + ks * 32);
  }

  f32x4 oacc[2][8] = {};
  float lacc[2][4] = {};   // independent partial denominators [qb][reg]

  auto stageK = [&](int buf, int t0) {
    char* dst = (char*)Ks[buf];
#pragma unroll
    for (int p = 0; p < 2; p++) {
      int D = p * 8192 + wave * 1024 + lane * 16;
      int row = D >> 8;
      int col2 = (D & 255) ^ ((row & 7) << 4);
      gload_lds16(Kb + ((long)b * S + t0 + row) * 128 + (col2 >> 1), dst + D);
    }
  };
  auto stageV = [&](int buf, int t0) {
    char* dst = (char*)VTs[buf];
#pragma unroll
    for (int p = 0; p < 2; p++) {
      int D = p * 8192 + wave * 1024 + lane * 16;
      int row = D >> 7;
      int colb = (D & 127) ^ ((row & 7) << 4);
      gload_lds16(VT + ((long)b * 128 + row) * 2048 + t0 + (colb >> 1), dst + D);
    }
  };

  stageK(0, 0);
  stageV(0, 0);
  __syncthreads();

  for (int t0 = 0; t0 < S; t0 += 64) {
    const int cur = (t0 >> 6) & 1;
    const bool nxt = (t0 + 64) < S;

    if (nxt) { stageK(cur ^ 1, t0 + 64); stageV(cur ^ 1, t0 + 64); }

    // QK^T swapped: A = K (t rows), B = Q (q cols).
    char* Ks3 = (char*)Ks[cur];
    f32x4 st[2][4] = {};
    __builtin_amdgcn_s_setprio(1);
#pragma unroll
    for (int ks = 0; ks < 4; ks++) {
#pragma unroll
      for (int nf = 0; nf < 4; nf++) {
        const int trow = nf * 16 + r;
        const int col2 = (ks * 64 + g * 16) ^ ((trow & 7) << 4);
        bf16x8 kf = *(const bf16x8*)(Ks3 + trow * 256 + col2);
        st[0][nf] = __builtin_amdgcn_mfma_f32_16x16x32_bf16(kf, qf[0][ks], st[0][nf], 0, 0, 0);
        st[1][nf] = __builtin_amdgcn_mfma_f32_16x16x32_bf16(kf, qf[1][ks], st[1][nf], 0, 0, 0);
      }
    }
    __builtin_amdgcn_s_setprio(0);

    // in-register softmax + P pack (compiler casts -> packed cvt)
    char* Vs3 = (char*)VTs[cur];
    bf16x8 vreg[2][8];
#pragma unroll
    for (int qb = 0; qb < 2; qb++) {
      bf16x8 pf[2];
#pragma unroll
      for (int ks = 0; ks < 2; ks++) {
        bf16x8 pv;
#pragma unroll
        for (int reg = 0; reg < 4; reg++) {
          float a = __builtin_amdgcn_exp2f(st[qb][ks * 2][reg]);
          float c = __builtin_amdgcn_exp2f(st[qb][ks * 2 + 1][reg]);
          lacc[qb][reg] += a + c;
          pv[reg] = (__bf16)a;
          pv[4 + reg] = (__bf16)c;
        }
        pf[ks] = pv;
      }
      // PV swapped: A = V^T (d rows), B = P (q cols); V frags cached qb0->qb1
      __builtin_amdgcn_s_setprio(1);
#pragma unroll
      for (int ks = 0; ks < 2; ks++) {
#pragma unroll
        for (int dn = 0; dn < 8; dn++) {
          if (qb == 0) {
            const int d = dn * 16 + r;
            vreg[ks][dn] = *(const bf16x8*)(Vs3 + d * 128 +
                                            ((ks * 64 + g * 16) ^ ((d & 7) << 4)));
          }
          oacc[qb][dn] = __builtin_amdgcn_mfma_f32_16x16x32_bf16(vreg[ks][dn], pf[ks],
                                                                 oacc[qb][dn], 0, 0, 0);
        }
      }
      __builtin_amdgcn_s_setprio(0);
    }

    __syncthreads();
  }

  // final denominator: combine partials, then reduce over g (t spread)
  float lsum[2];
#pragma unroll
  for (int qb = 0; qb < 2; qb++) {
    lsum[qb] = (lacc[qb][0] + lacc[qb][1]) + (lacc[qb][2] + lacc[qb][3]);
    lsum[qb] += __shfl_xor(lsum[qb], 16);
    lsum[qb] += __shfl_xor(lsum[qb], 32);
  }

  // epilogue: oacc[qb][dn]: row q = r, d = dn*16 + g*4 + reg
#pragma unroll
  for (int qb = 0; qb < 2; qb++) {
    const float inv = 1.f / lsum[qb];
    const long orow = (long)(b * S + qt * 256 + qb * 128 + wave * 16 + r);
#pragma unroll
    for (int dn = 0; dn < 8; dn++) {
      u16 pk4[4];
#pragma unroll
      for (int reg = 0; reg < 4; reg++) pk4[reg] = f2bf(oacc[qb][dn][reg] * inv);
      *(ushort4*)(O + orow * 2048 + head * 128 + dn * 16 + g * 4) =
          *(const ushort4*)pk4;
    }
  }
}

// ---------------- launch ----------------
extern "C" void kernel_launch(void* const* d_in, const int* in_sizes, int n_in,
                              void* d_out, int out_size, void* d_ws, size_t ws_size,
                              hipStream_t stream) {
  const float* x  = (const float*)d_in[0];
  const float* Wq = (const float*)d_in[1];
  const float* bq = (const float*)d_in[2];
  const float* Wk = (const float*)d_in[3];
  const float* bk = (const float*)d_in[4];
  const float* Wv = (const float*)d_in[5];
  const float* bv = (const float*)d_in[6];
  const float* Wo = (const float*)d_in[7];
  const float* bo = (const float*)d_in[8];
  float* out = (float*)d_out;

  char* ws = (char*)d_ws;
  u16* x_bf     = (u16*)(ws + (0ul  << 20));  // 16 MiB
  u16* q_bf     = (u16*)(ws + (16ul << 20));  // 16 MiB
  u16* wqkv_bf  = (u16*)(ws + (32ul << 20));  // 9 MiB  [2304][2048]
  u16* wo_bf    = (u16*)(ws + (42ul << 20));  // 8 MiB
  u16* k_bf     = (u16*)(ws + (50ul << 20));  // 1 MiB  K   [b*S][128]
  u16* vt_bf    = (u16*)(ws + (51ul << 20));  // 1 MiB  V^T [b*128][2048] t_lin
  u16* attn_bf  = (u16*)(ws + (52ul << 20));  // 16 MiB (aliases kv partials)
  float* kvp    = (float*)(ws + (52ul << 20)); // 16 MiB fp32 [4][4096][256]
  float* bias_a = (float*)(ws + (68ul << 20));

  const float QS = 0.12751744f;  // log2(e)/sqrt(128)

  cvt_all<<<8457, 256, 0, stream>>>(x, Wq, Wk, Wv, Wo, bq, bk, bv,
                                    x_bf, wqkv_bf, wo_bf, bias_a, QS);

  // Q projection: known-good launch config (N=2048, grid 16x32)
  gemm_q<<<dim3(16, 32), 256, 0, stream>>>(x_bf, wqkv_bf, bias_a, q_bf, 2048);
  // KV projection: split-K partials (256 blocks, one round)
  gemm_kv<<<dim3(2, 32, 4), 256, 0, stream>>>(
      x_bf, wqkv_bf + 2048l * 2048, kvp);
  // sum partials + bias -> K rows + V^T (t_lin)
  kv_finish<<<4096, 256, 0, stream>>>(kvp, bias_a, k_bf, vt_bf);
  // attention -> [4096, 2048] bf16 (overwrites kvp region with its output)
  attn_mqa15<<<256, 512, 0, stream>>>(q_bf, k_bf, vt_bf, attn_bf);
  // out = attn Wo^T + bo  (fp32)
  gemm_out<<<dim3(16, 32), 256, 0, stream>>>(
      attn_bf, wo_bf, bo, out, 2048, 2048);
}